// Round 7
// baseline (161.878 us; speedup 1.0000x reference)
//
#include <hip/hip_runtime.h>

typedef float f32x16 __attribute__((ext_vector_type(16)));
typedef float f32x4  __attribute__((ext_vector_type(4)));
typedef float f32x2  __attribute__((ext_vector_type(2)));
typedef short bf16x8 __attribute__((ext_vector_type(8)));

#define NB 16
#define CI 64
#define CO 64
#define Hh 128
#define Ww 128

// A layout: short index (((tap*2+kc)*8 + mg)*2 + ks_in)*512 + l*8 + e
//   m = mg*32 + r ; py = mg>>2, och = mg&3, oc = och*16 + (r>>1), px = r&1 (r = l&31)
//   ic = (kc*2+ks_in)*16 + (l>>5)*8 + e
// Per-(tap,kc,z) slice for mg in {2z,2z+1} is 4 KB contiguous.
__device__ short g_A[9 * 2 * 8 * 2 * 64 * 8];        // 288 KB (L2-resident)
__device__ short g_xh[(size_t)NB * Hh * Ww * CI];    // x in NHWC bf16, 33.5 MB

__device__ inline short f2bf(float f) {
  union { float f; unsigned u; } v; v.f = f;
  unsigned r = (v.u + 0x7FFF + ((v.u >> 16) & 1)) >> 16;   // RNE
  return (short)r;
}

// Merged prep: blocks [0,2048) = NCHW fp32 -> NHWC bf16; [2048,2112) = filters.
__global__ __launch_bounds__(256) void prep(const float* __restrict__ x,
                                            const float* __restrict__ w) {
  const int tid = threadIdx.x;
  if (blockIdx.x >= 2048) {
    const int base = (blockIdx.x - 2048) * 2304;
    #pragma unroll
    for (int i = 0; i < 9; ++i) {
      const int ef = base + i * 256 + tid;
      const int e     = ef & 7;
      const int l     = (ef >> 3) & 63;
      const int ks_in = (ef >> 9) & 1;
      const int mg    = (ef >> 10) & 7;
      const int kc    = (ef >> 13) & 1;
      const int tap   = ef >> 14;
      const int r   = l & 31;
      const int px  = r & 1;
      const int py  = mg >> 2;
      const int oc  = (mg & 3) * 16 + (r >> 1);
      const int ic  = (kc * 2 + ks_in) * 16 + (l >> 5) * 8 + e;
      const int dyi = tap / 3, dxi = tap % 3;
      const int my = 2 * dyi + 1 - py;      // composite 6-tap index for this parity
      const int mx = 2 * dxi + 1 - px;
      const float FF[4] = {0.25f, 0.75f, 0.75f, 0.25f}; // [1,3,3,1]/4 incl. up^2 gain
      const float* wp = w + (oc * CI + ic) * 9;
      float s = 0.f;
      #pragma unroll
      for (int ky = 0; ky < 3; ++ky) {
        const int iy = my - ky;
        if (iy < 0 || iy > 3) continue;
        #pragma unroll
        for (int kx = 0; kx < 3; ++kx) {
          const int ix = mx - kx;
          if (ix < 0 || ix > 3) continue;
          s += wp[(2 - ky) * 3 + (2 - kx)] * (FF[iy] * FF[ix]); // true conv: flipped w
        }
      }
      g_A[ef] = f2bf(s * (1.0f / 24.0f));   // WEIGHT_GAIN = 1/sqrt(64*9)
    }
    return;
  }
  // ---- NCHW -> NHWC via LDS transpose, coalesced both sides ----
  __shared__ alignas(16) char xt[64 * 512];          // 32 KB fp32, XOR-granule swizzle
  const int b = blockIdx.x;                 // (n, y)
  const int n = b >> 7, y = b & 127;
  #pragma unroll
  for (int it = 0; it < 8; ++it) {
    const int idx = tid + it * 256;         // 0..2047 float4 units
    const int ic = idx >> 5, xq = idx & 31;
    const f32x4 v = *(const f32x4*)(x + (((size_t)n * CI + ic) * Hh + y) * Ww + xq * 4);
    *(f32x4*)(xt + ic * 512 + ((xq * 16) ^ (((ic >> 3) & 7) * 16))) = v;
  }
  __syncthreads();
  #pragma unroll
  for (int it = 0; it < 4; ++it) {
    const int idx = tid + it * 256;         // 0..1023
    const int icb = idx & 7, xp = idx >> 3; // xp 0..127
    bf16x8 o;
    #pragma unroll
    for (int j = 0; j < 8; ++j) {
      const int ic = icb * 8 + j;
      const float f = *(const float*)(xt + ic * 512 + (((xp >> 2) * 16) ^ (icb * 16)) + (xp & 3) * 4);
      o[j] = f2bf(f);
    }
    *(bf16x8*)(g_xh + (((size_t)n * Hh + y) * Ww + xp) * CI + icb * 8) = o;
  }
}

// Conv: block = 256 thr (4 waves), M=64 (mg {2z,2z+1}) x N=512 (128p x 4q, wave = 1 q-row).
// A staged per-(kc,tap) into LDS dbuf via global_load_lds; xs ic-split into 2 kc halves.
#define CH 12480      // xs chunk stride: 6 rows * 130 pix * 16 B
#define AB 49920      // A-dbuf base (after 4 chunks)

__global__ __launch_bounds__(256, 2) void mfma_conv(const float* __restrict__ bias,
                                                    float* __restrict__ out) {
  __shared__ alignas(16) char lds[58112];   // 4*CH xs + 2*4096 A

  const int tid = threadIdx.x;
  const int l   = tid & 63;
  const int wid = tid >> 6;                 // wave = output row q = qb + wid
  const int n   = blockIdx.y;
  const int z   = blockIdx.x & 3;           // M-slice: mg in {2z, 2z+1}
  const int qt  = blockIdx.x >> 2;
  const int qb  = qt * 4;

  auto stageA = [&](int tap, int kc, int buf) {
    const char* gs = (const char*)g_A + ((tap * 2 + kc) * 16 + 4 * z) * 1024 + tid * 16;
    char* ls = (char*)lds + AB + buf * 4096 + wid * 1024;   // wave-uniform base
    __builtin_amdgcn_global_load_lds(
        (const __attribute__((address_space(1))) unsigned*)gs,
        (__attribute__((address_space(3))) unsigned*)ls, 16, 0, 0);
  };

  stageA(0, 0, 0);                          // prefetch first A slice

  f32x16 acc[2][4];                         // [mf][nf]
  #pragma unroll
  for (int mf = 0; mf < 2; ++mf)
    #pragma unroll
    for (int nf = 0; nf < 4; ++nf)
      #pragma unroll
      for (int r = 0; r < 16; ++r) acc[mf][nf][r] = 0.f;

  const int col = l & 31, kg2 = l >> 5;
  const size_t xbase = (size_t)n * (Hh * Ww * CI);

  #pragma unroll
  for (int kc = 0; kc < 2; ++kc) {
    __syncthreads();                        // xs free to overwrite
    // ---- stage xs: 6 rows x 130 pix x 32 ic (this kc half), pix-major coalesced ----
    for (int u = tid; u < 3120; u += 256) { // 780 pix * 4 icb
      const int icb = u & 3, idx = u >> 2;
      const int row = idx / 130, colh = idx - row * 130;
      const int gy = qb - 1 + row, gx = colh - 1;
      bf16x8 v = {};
      if ((unsigned)gy < (unsigned)Hh && (unsigned)gx < (unsigned)Ww)
        v = *(const bf16x8*)(g_xh + xbase + (size_t)(gy * Ww + gx) * CI + kc * 32 + icb * 8);
      *(bf16x8*)(lds + icb * CH + idx * 16) = v;
    }
    #pragma unroll
    for (int tap = 0; tap < 9; ++tap) {
      const int s = kc * 9 + tap;
      asm volatile("s_waitcnt vmcnt(0)" ::: "memory");  // A(s) landed
      __syncthreads();                                   // + xs writes visible
      if (tap < 8) stageA(tap + 1, kc, (s + 1) & 1);
      else if (kc == 0) stageA(0, 1, (s + 1) & 1);
      const int dyi = tap / 3, dxi = tap % 3;
      const int abuf = AB + (s & 1) * 4096;
      #pragma unroll
      for (int ks = 0; ks < 2; ++ks) {
        bf16x8 a[2], b[4];
        #pragma unroll
        for (int mf = 0; mf < 2; ++mf)
          a[mf] = *(const bf16x8*)(lds + abuf + (mf * 2 + ks) * 1024 + l * 16);
        #pragma unroll
        for (int nf = 0; nf < 4; ++nf)
          b[nf] = *(const bf16x8*)(lds + (ks * 2 + kg2) * CH +
                                   ((wid + dyi) * 130 + nf * 32 + col + dxi) * 16);
        __builtin_amdgcn_s_setprio(1);
        #pragma unroll
        for (int mf = 0; mf < 2; ++mf)
          #pragma unroll
          for (int nf = 0; nf < 4; ++nf)
            acc[mf][nf] = __builtin_amdgcn_mfma_f32_32x32x16_bf16(a[mf], b[nf], acc[mf][nf], 0, 0, 0);
        __builtin_amdgcn_s_setprio(0);
      }
    }
  }

  // ---- epilogue: bias + lrelu*sqrt2 + clamp; in-lane px pairs -> dense f32x2 stores ----
  float* outp = out + ((size_t)(n * CO) << 16);
  const int q = qb + wid;
  #pragma unroll
  for (int mf = 0; mf < 2; ++mf) {
    const int mg = 2 * z + mf;
    const int py = mg >> 2, och = mg & 3;
    const int y = 2 * q + py;
    #pragma unroll
    for (int nf = 0; nf < 4; ++nf) {
      const int xd = 2 * (nf * 32 + col);
      #pragma unroll
      for (int rp = 0; rp < 8; ++rp) {
        const int oc = och * 16 + (rp & 1) + 4 * (rp >> 1) + 2 * kg2;
        const float bj = bias[oc];
        float v0 = acc[mf][nf][2 * rp]     + bj;
        float v1 = acc[mf][nf][2 * rp + 1] + bj;
        v0 = (v0 >= 0.f ? v0 : 0.2f * v0) * 1.4142135623730951f;
        v1 = (v1 >= 0.f ? v1 : 0.2f * v1) * 1.4142135623730951f;
        v0 = fminf(256.f, fmaxf(-256.f, v0));
        v1 = fminf(256.f, fmaxf(-256.f, v1));
        f32x2 o; o[0] = v0; o[1] = v1;
        *(f32x2*)(outp + ((size_t)oc << 16) + y * 256 + xd) = o;
      }
    }
  }
}

extern "C" void kernel_launch(void* const* d_in, const int* in_sizes, int n_in,
                              void* d_out, int out_size, void* d_ws, size_t ws_size,
                              hipStream_t stream) {
  const float* x    = (const float*)d_in[0];
  const float* w    = (const float*)d_in[1];
  const float* bias = (const float*)d_in[2];
  float* out = (float*)d_out;

  prep<<<2112, 256, 0, stream>>>(x, w);
  mfma_conv<<<dim3(128, NB), 256, 0, stream>>>(bias, out);
}

// Round 8
// 147.586 us; speedup vs baseline: 1.0968x; 1.0968x over previous
//
#include <hip/hip_runtime.h>

typedef float f32x16 __attribute__((ext_vector_type(16)));
typedef float f32x4  __attribute__((ext_vector_type(4)));
typedef float f32x2  __attribute__((ext_vector_type(2)));
typedef short bf16x8 __attribute__((ext_vector_type(8)));

#define NB 16
#define CI 64
#define CO 64
#define Hh 128
#define Ww 128

// A in 32x32x16-fragment order: short index ((tap*4+ks)*8 + mg)*512 + l*8 + e
// M-remap (px in-lane): m = mg*32 + r ; py = mg>>2, och = mg&3, oc = och*16 + (r>>1), px = r&1
// k: ic = ks*16 + (l>>5)*8 + e
__device__ short g_A[9 * 4 * 8 * 64 * 8];            // 288 KB (L2-resident)
__device__ short g_xh[(size_t)NB * Hh * Ww * CI];    // x in NHWC bf16, 33.5 MB

__device__ inline short f2bf(float f) {
  union { float f; unsigned u; } v; v.f = f;
  unsigned r = (v.u + 0x7FFF + ((v.u >> 16) & 1)) >> 16;   // RNE
  return (short)r;
}

// Merged prep: blocks [0,2048) = NCHW fp32 -> NHWC bf16; [2048,2112) = filters (R4 layout).
__global__ __launch_bounds__(256) void prep(const float* __restrict__ x,
                                            const float* __restrict__ w) {
  const int tid = threadIdx.x;
  if (blockIdx.x >= 2048) {
    const int base = (blockIdx.x - 2048) * 2304;
    #pragma unroll
    for (int i = 0; i < 9; ++i) {
      const int ef = base + i * 256 + tid;
      const int e   = ef & 7;
      const int l   = (ef >> 3) & 63;
      const int mg  = (ef >> 9) & 7;
      const int ks  = (ef >> 12) & 3;
      const int tap = ef >> 14;
      const int r   = l & 31;
      const int px  = r & 1;
      const int py  = mg >> 2;
      const int oc  = (mg & 3) * 16 + (r >> 1);
      const int ic  = ks * 16 + (l >> 5) * 8 + e;
      const int dyi = tap / 3, dxi = tap % 3;
      const int my = 2 * dyi + 1 - py;      // composite 6-tap index for this parity
      const int mx = 2 * dxi + 1 - px;
      const float FF[4] = {0.25f, 0.75f, 0.75f, 0.25f}; // [1,3,3,1]/4 incl. up^2 gain
      const float* wp = w + (oc * CI + ic) * 9;
      float s = 0.f;
      #pragma unroll
      for (int ky = 0; ky < 3; ++ky) {
        const int iy = my - ky;
        if (iy < 0 || iy > 3) continue;
        #pragma unroll
        for (int kx = 0; kx < 3; ++kx) {
          const int ix = mx - kx;
          if (ix < 0 || ix > 3) continue;
          s += wp[(2 - ky) * 3 + (2 - kx)] * (FF[iy] * FF[ix]); // true conv: flipped w
        }
      }
      g_A[ef] = f2bf(s * (1.0f / 24.0f));   // WEIGHT_GAIN = 1/sqrt(64*9)
    }
    return;
  }
  // ---- NCHW -> NHWC via LDS transpose, coalesced both sides ----
  __shared__ alignas(16) char xt[64 * 512];          // 32 KB fp32, XOR-granule swizzle
  const int b = blockIdx.x;                 // (n, y)
  const int n = b >> 7, y = b & 127;
  #pragma unroll
  for (int it = 0; it < 8; ++it) {
    const int idx = tid + it * 256;         // 0..2047 float4 units
    const int ic = idx >> 5, xq = idx & 31;
    const f32x4 v = *(const f32x4*)(x + (((size_t)n * CI + ic) * Hh + y) * Ww + xq * 4);
    *(f32x4*)(xt + ic * 512 + ((xq * 16) ^ (((ic >> 3) & 7) * 16))) = v;
  }
  __syncthreads();
  #pragma unroll
  for (int it = 0; it < 4; ++it) {
    const int idx = tid + it * 256;         // 0..1023
    const int icb = idx & 7, xp = idx >> 3; // xp 0..127
    bf16x8 o;
    #pragma unroll
    for (int j = 0; j < 8; ++j) {
      const int ic = icb * 8 + j;
      const float f = *(const float*)(xt + ic * 512 + (((xp >> 2) * 16) ^ (icb * 16)) + (xp & 3) * 4);
      o[j] = f2bf(f);
    }
    *(bf16x8*)(g_xh + (((size_t)n * Hh + y) * Ww + xp) * CI + icb * 8) = o;
  }
}

// Main conv (R4 geometry, M-half split): block = 256 thr (4 waves = wm2 x wn2),
// M=256 x N=128 (16p x 8q pos tile). Wave = mf4 x nf2, run as TWO mf-halves with
// the epilogue of half 0 issued before half 1's compute (store/compute stagger).
#define CH_STR 2896   // 180 pix * 16B + 16 pad

__global__ __launch_bounds__(256, 3) void mfma_conv(const float* __restrict__ bias,
                                                    float* __restrict__ out) {
  __shared__ alignas(16) char xs[8 * CH_STR];        // 23168 B

  const int tid = threadIdx.x;
  const int l   = tid & 63;
  const int wid = tid >> 6;                 // 4 waves
  const int wm  = wid >> 1;                 // M half-of-wave-group (mg = wm*4 + mf)
  const int wn  = wid & 1;                  // N half
  const int n   = blockIdx.y;
  const int ty0 = blockIdx.x >> 3, tx0 = blockIdx.x & 7;
  const int qb  = ty0 * 8, pb = tx0 * 16;

  // ---- stage 10x18x64 halo into chunked LDS ----
  const size_t xbase = (size_t)n * (Hh * Ww * CI);
  for (int u = tid; u < 1440; u += 256) {   // 180 pix * 8 chunks
    const int icb8 = u & 7, pix = u >> 3;
    const int yy = pix / 18, xx = pix - yy * 18;
    const int gy = qb - 1 + yy, gx = pb - 1 + xx;
    bf16x8 v = {};
    if ((unsigned)gy < (unsigned)Hh && (unsigned)gx < (unsigned)Ww)
      v = *(const bf16x8*)(g_xh + xbase + (size_t)(gy * Ww + gx) * CI + icb8 * 8);
    *(bf16x8*)(xs + icb8 * CH_STR + pix * 16) = v;
  }
  __syncthreads();                          // the only barrier

  const int col = l & 31, kg2 = l >> 5;
  const int p = col & 15, qh = col >> 4;    // pos = wn*64 + nf*32 + col -> q, p
  int bbase[2];
  #pragma unroll
  for (int nf = 0; nf < 2; ++nf)
    bbase[nf] = kg2 * CH_STR + ((wn * 4 + nf * 2 + qh) * 18 + p) * 16;

  float* outp = out + ((size_t)(n * CO) << 16);

  #pragma unroll
  for (int h = 0; h < 2; ++h) {             // mf-half: mf = h*2 + m2
    // ---- load this half's tap-0 A fragments ----
    bf16x8 a[4][2];                         // [ks][m2]
    #pragma unroll
    for (int ks = 0; ks < 4; ++ks)
      #pragma unroll
      for (int m2 = 0; m2 < 2; ++m2)
        a[ks][m2] = *(const bf16x8*)(g_A + (ks * 8 + wm * 4 + h * 2 + m2) * 512 + l * 8);

    f32x16 acc[2][2];
    #pragma unroll
    for (int m2 = 0; m2 < 2; ++m2)
      #pragma unroll
      for (int nf = 0; nf < 2; ++nf)
        #pragma unroll
        for (int r = 0; r < 16; ++r) acc[m2][nf][r] = 0.f;

    #pragma unroll
    for (int tap = 0; tap < 9; ++tap) {
      const int dyi = tap / 3, dxi = tap % 3;
      const int bsh = (dyi * 18 + dxi) * 16;
      #pragma unroll
      for (int ks = 0; ks < 4; ++ks) {
        bf16x8 b[2];
        #pragma unroll
        for (int nf = 0; nf < 2; ++nf)
          b[nf] = *(const bf16x8*)(xs + bbase[nf] + ks * (2 * CH_STR) + bsh);
        __builtin_amdgcn_s_setprio(1);
        #pragma unroll
        for (int m2 = 0; m2 < 2; ++m2)
          #pragma unroll
          for (int nf = 0; nf < 2; ++nf)
            acc[m2][nf] = __builtin_amdgcn_mfma_f32_32x32x16_bf16(a[ks][m2], b[nf], acc[m2][nf], 0, 0, 0);
        __builtin_amdgcn_s_setprio(0);
        if (tap < 8) {                      // reload a[ks] for tap+1 (regs just freed)
          #pragma unroll
          for (int m2 = 0; m2 < 2; ++m2)
            a[ks][m2] = *(const bf16x8*)(g_A + (((tap + 1) * 4 + ks) * 8 + wm * 4 + h * 2 + m2) * 512 + l * 8);
        }
      }
    }

    // ---- epilogue for this half: stores drain under the other half's compute ----
    #pragma unroll
    for (int m2 = 0; m2 < 2; ++m2) {
      const int mg = wm * 4 + h * 2 + m2;
      const int py = mg >> 2, och = mg & 3;
      #pragma unroll
      for (int nf = 0; nf < 2; ++nf) {
        const int q = wn * 4 + nf * 2 + qh;
        const int y = 2 * (qb + q) + py;
        const int xd = 2 * (pb + p);
        #pragma unroll
        for (int rp = 0; rp < 8; ++rp) {
          const int oc = och * 16 + (rp & 1) + 4 * (rp >> 1) + 2 * kg2;
          const float bj = bias[oc];
          float v0 = acc[m2][nf][2 * rp]     + bj;
          float v1 = acc[m2][nf][2 * rp + 1] + bj;
          v0 = (v0 >= 0.f ? v0 : 0.2f * v0) * 1.4142135623730951f;
          v1 = (v1 >= 0.f ? v1 : 0.2f * v1) * 1.4142135623730951f;
          v0 = fminf(256.f, fmaxf(-256.f, v0));
          v1 = fminf(256.f, fmaxf(-256.f, v1));
          f32x2 o; o[0] = v0; o[1] = v1;
          *(f32x2*)(outp + ((size_t)oc << 16) + y * 256 + xd) = o;
        }
      }
    }
  }
}

extern "C" void kernel_launch(void* const* d_in, const int* in_sizes, int n_in,
                              void* d_out, int out_size, void* d_ws, size_t ws_size,
                              hipStream_t stream) {
  const float* x    = (const float*)d_in[0];
  const float* w    = (const float*)d_in[1];
  const float* bias = (const float*)d_in[2];
  float* out = (float*)d_out;

  prep<<<2112, 256, 0, stream>>>(x, w);
  mfma_conv<<<dim3(128, NB), 256, 0, stream>>>(bias, out);
}

// Round 9
// 123.752 us; speedup vs baseline: 1.3081x; 1.1926x over previous
//
#include <hip/hip_runtime.h>

typedef float f32x16 __attribute__((ext_vector_type(16)));
typedef float f32x4  __attribute__((ext_vector_type(4)));
typedef float f32x2  __attribute__((ext_vector_type(2)));
typedef short bf16x8 __attribute__((ext_vector_type(8)));

#define NB 16
#define CI 64
#define CO 64
#define Hh 128
#define Ww 128

// A in 32x32x16-fragment order: short index ((tap*4+ks)*8 + mg)*512 + l*8 + e
// M-remap (px in-lane): m = mg*32 + r ; py = mg>>2, och = mg&3, oc = och*16 + (r>>1), px = r&1
// k: ic = ks*16 + (l>>5)*8 + e
__device__ short g_A[9 * 4 * 8 * 64 * 8];            // 288 KB (L2-resident)
__device__ short g_xh[(size_t)NB * Hh * Ww * CI];    // x in NHWC bf16, 33.5 MB

__device__ inline short f2bf(float f) {
  union { float f; unsigned u; } v; v.f = f;
  unsigned r = (v.u + 0x7FFF + ((v.u >> 16) & 1)) >> 16;   // RNE
  return (short)r;
}

// Merged prep: blocks [0,2048) = NCHW fp32 -> NHWC bf16; [2048,2112) = filters (R4 layout).
__global__ __launch_bounds__(256) void prep(const float* __restrict__ x,
                                            const float* __restrict__ w) {
  const int tid = threadIdx.x;
  if (blockIdx.x >= 2048) {
    const int base = (blockIdx.x - 2048) * 2304;
    #pragma unroll
    for (int i = 0; i < 9; ++i) {
      const int ef = base + i * 256 + tid;
      const int e   = ef & 7;
      const int l   = (ef >> 3) & 63;
      const int mg  = (ef >> 9) & 7;
      const int ks  = (ef >> 12) & 3;
      const int tap = ef >> 14;
      const int r   = l & 31;
      const int px  = r & 1;
      const int py  = mg >> 2;
      const int oc  = (mg & 3) * 16 + (r >> 1);
      const int ic  = ks * 16 + (l >> 5) * 8 + e;
      const int dyi = tap / 3, dxi = tap % 3;
      const int my = 2 * dyi + 1 - py;      // composite 6-tap index for this parity
      const int mx = 2 * dxi + 1 - px;
      const float FF[4] = {0.25f, 0.75f, 0.75f, 0.25f}; // [1,3,3,1]/4 incl. up^2 gain
      const float* wp = w + (oc * CI + ic) * 9;
      float s = 0.f;
      #pragma unroll
      for (int ky = 0; ky < 3; ++ky) {
        const int iy = my - ky;
        if (iy < 0 || iy > 3) continue;
        #pragma unroll
        for (int kx = 0; kx < 3; ++kx) {
          const int ix = mx - kx;
          if (ix < 0 || ix > 3) continue;
          s += wp[(2 - ky) * 3 + (2 - kx)] * (FF[iy] * FF[ix]); // true conv: flipped w
        }
      }
      g_A[ef] = f2bf(s * (1.0f / 24.0f));   // WEIGHT_GAIN = 1/sqrt(64*9)
    }
    return;
  }
  // ---- NCHW -> NHWC via LDS transpose, coalesced both sides ----
  __shared__ alignas(16) char xt[64 * 512];          // 32 KB fp32, XOR-granule swizzle
  const int b = blockIdx.x;                 // (n, y)
  const int n = b >> 7, y = b & 127;
  #pragma unroll
  for (int it = 0; it < 8; ++it) {
    const int idx = tid + it * 256;         // 0..2047 float4 units
    const int ic = idx >> 5, xq = idx & 31;
    const f32x4 v = *(const f32x4*)(x + (((size_t)n * CI + ic) * Hh + y) * Ww + xq * 4);
    *(f32x4*)(xt + ic * 512 + ((xq * 16) ^ (((ic >> 3) & 7) * 16))) = v;
  }
  __syncthreads();
  #pragma unroll
  for (int it = 0; it < 4; ++it) {
    const int idx = tid + it * 256;         // 0..1023
    const int icb = idx & 7, xp = idx >> 3; // xp 0..127
    bf16x8 o;
    #pragma unroll
    for (int j = 0; j < 8; ++j) {
      const int ic = icb * 8 + j;
      const float f = *(const float*)(xt + ic * 512 + (((xp >> 2) * 16) ^ (icb * 16)) + (xp & 3) * 4);
      o[j] = f2bf(f);
    }
    *(bf16x8*)(g_xh + (((size_t)n * Hh + y) * Ww + xp) * CI + icb * 8) = o;
  }
}

// Main conv (R4 structure, wide tile): block = 256 thr (4 waves = wm2 x wn2),
// M=256 x N=128 positions as a 64p x 2q tile. Wave = mf4 x nf2, owns ONE output
// row y -> each NT f32x2 store instruction writes 2 dense 256-B segments.
#define CH_STR 4240   // 264 pix * 16 B + 16 pad

__global__ __launch_bounds__(256, 2) void mfma_conv(const float* __restrict__ bias,
                                                    float* __restrict__ out) {
  __shared__ alignas(16) char xs[8 * CH_STR];        // 33920 B

  const int tid = threadIdx.x;
  const int l   = tid & 63;
  const int wid = tid >> 6;                 // 4 waves
  const int wm  = wid >> 1;                 // M half (mg = wm*4 + mf)
  const int wn  = wid & 1;                  // q row within tile
  const int n   = blockIdx.y;
  const int ty0 = blockIdx.x >> 1, tx0 = blockIdx.x & 1;
  const int qb  = ty0 * 2, pb = tx0 * 64;

  // ---- issue tap-0 A-fragment loads early (latency hides under staging) ----
  bf16x8 a[4][4];                           // [ks][mf]
  #pragma unroll
  for (int ks = 0; ks < 4; ++ks)
    #pragma unroll
    for (int mf = 0; mf < 4; ++mf)
      a[ks][mf] = *(const bf16x8*)(g_A + (ks * 8 + wm * 4 + mf) * 512 + l * 8);

  // ---- stage 4x66x64 halo into chunked LDS ----
  const size_t xbase = (size_t)n * (Hh * Ww * CI);
  for (int u = tid; u < 2112; u += 256) {   // 264 pix * 8 chunks
    const int icb8 = u & 7, pix = u >> 3;
    const int yy = pix / 66, xx = pix - yy * 66;
    const int gy = qb - 1 + yy, gx = pb - 1 + xx;
    bf16x8 v = {};
    if ((unsigned)gy < (unsigned)Hh && (unsigned)gx < (unsigned)Ww)
      v = *(const bf16x8*)(g_xh + xbase + (size_t)(gy * Ww + gx) * CI + icb8 * 8);
    *(bf16x8*)(xs + icb8 * CH_STR + pix * 16) = v;
  }
  __syncthreads();                          // the only barrier

  f32x16 acc[4][2];
  #pragma unroll
  for (int mf = 0; mf < 4; ++mf)
    #pragma unroll
    for (int nf = 0; nf < 2; ++nf)
      #pragma unroll
      for (int r = 0; r < 16; ++r) acc[mf][nf][r] = 0.f;

  const int col = l & 31, kg2 = l >> 5;
  // pos = wn*64 + nf*32 + col -> q = wn, p = nf*32 + col
  int bbase[2];
  #pragma unroll
  for (int nf = 0; nf < 2; ++nf)
    bbase[nf] = kg2 * CH_STR + (wn * 66 + nf * 32 + col) * 16;

  #pragma unroll
  for (int tap = 0; tap < 9; ++tap) {
    const int dyi = tap / 3, dxi = tap % 3;
    const int bsh = (dyi * 66 + dxi) * 16;
    #pragma unroll
    for (int ks = 0; ks < 4; ++ks) {
      bf16x8 b[2];
      #pragma unroll
      for (int nf = 0; nf < 2; ++nf)
        b[nf] = *(const bf16x8*)(xs + bbase[nf] + ks * (2 * CH_STR) + bsh);
      __builtin_amdgcn_s_setprio(1);
      #pragma unroll
      for (int mf = 0; mf < 4; ++mf)
        #pragma unroll
        for (int nf = 0; nf < 2; ++nf)
          acc[mf][nf] = __builtin_amdgcn_mfma_f32_32x32x16_bf16(a[ks][mf], b[nf], acc[mf][nf], 0, 0, 0);
      __builtin_amdgcn_s_setprio(0);
      if (tap < 8) {                        // reload a[ks] for tap+1 (regs just freed)
        #pragma unroll
        for (int mf = 0; mf < 4; ++mf)
          a[ks][mf] = *(const bf16x8*)(g_A + (((tap + 1) * 4 + ks) * 8 + wm * 4 + mf) * 512 + l * 8);
      }
    }
  }

  // ---- epilogue: bias + lrelu*sqrt2 + clamp; wave owns one y row ->
  //      each NT f32x2 store = 2 dense 256-B segments (32 lanes x 8 B) ----
  float* outp = out + ((size_t)(n * CO) << 16);
  const int y = 2 * (qb + wn) + wm;         // py = wm
  #pragma unroll
  for (int mf = 0; mf < 4; ++mf) {
    #pragma unroll
    for (int nf = 0; nf < 2; ++nf) {
      const int xd = 2 * (pb + nf * 32 + col);
      #pragma unroll
      for (int rp = 0; rp < 8; ++rp) {
        const int oc = mf * 16 + (rp & 1) + 4 * (rp >> 1) + 2 * kg2;
        const float bj = bias[oc];
        float v0 = acc[mf][nf][2 * rp]     + bj;
        float v1 = acc[mf][nf][2 * rp + 1] + bj;
        v0 = (v0 >= 0.f ? v0 : 0.2f * v0) * 1.4142135623730951f;
        v1 = (v1 >= 0.f ? v1 : 0.2f * v1) * 1.4142135623730951f;
        v0 = fminf(256.f, fmaxf(-256.f, v0));
        v1 = fminf(256.f, fmaxf(-256.f, v1));
        f32x2 o; o[0] = v0; o[1] = v1;
        __builtin_nontemporal_store(o, (f32x2*)(outp + ((size_t)oc << 16) + y * 256 + xd));
      }
    }
  }
}

extern "C" void kernel_launch(void* const* d_in, const int* in_sizes, int n_in,
                              void* d_out, int out_size, void* d_ws, size_t ws_size,
                              hipStream_t stream) {
  const float* x    = (const float*)d_in[0];
  const float* w    = (const float*)d_in[1];
  const float* bias = (const float*)d_in[2];
  float* out = (float*)d_out;

  prep<<<2112, 256, 0, stream>>>(x, w);
  mfma_conv<<<dim3(128, NB), 256, 0, stream>>>(bias, out);
}